// Round 4
// baseline (362.575 us; speedup 1.0000x reference)
//
#include <hip/hip_runtime.h>
#include <hip/hip_bf16.h>

#define N_NODES 8192
#define F_IN    128
#define F_OUT   64
#define N_EDGES 262144

typedef unsigned int   u32;
typedef unsigned short u16;
typedef __attribute__((ext_vector_type(8))) short short8;
typedef __attribute__((ext_vector_type(4))) float f32x4;
typedef __attribute__((ext_vector_type(4))) u32 u32x4;

// chunk swizzle (16B chunks, 16 per row): XOR of a 3-bit mix of row bits.
// Involution in ch for fixed r; spreads 16-row frag reads across 8 bank-quads.
__device__ __forceinline__ int SWZ(int r) {
    return (((r) & 3) << 1) | (((r) >> 2) & 1);
}

__device__ __forceinline__ u16 f2bf_rne(float f) {
    u32 u = __float_as_uint(f);
    u32 r = (u + 0x7FFFu + ((u >> 16) & 1u)) >> 16;
    return (u16)r;
}
__device__ __forceinline__ float bf2f(u16 b) {
    return __uint_as_float(((u32)b) << 16);
}

// ---------------------------------------------------------------------------
// init: blocks 0..31 detect edge width; block 32 detects x dtype;
// blocks 33..64 zero deg[8192]. Flags pre-zeroed by a 32-B memset.
// ---------------------------------------------------------------------------
__global__ __launch_bounds__(256) void init_kernel(const int* __restrict__ ei,
                                                   const u32* __restrict__ xw,
                                                   int* __restrict__ eflag,
                                                   int* __restrict__ xdt,
                                                   int* __restrict__ deg) {
    if (blockIdx.x < 32) {
        int i = blockIdx.x * 256 + threadIdx.x;      // 8192 samples
        if (ei[2 * i + 1] != 0) atomicOr(eflag, 1);
    } else if (blockIdx.x == 32) {
        __shared__ int cnt;
        if (threadIdx.x == 0) cnt = 0;
        __syncthreads();
        u32 w = xw[threadIdx.x * 64 + 1];
        u32 e = (w >> 7) & 0xFFu;
        if (e >= 100u && e <= 134u) atomicAdd(&cnt, 1);
        __syncthreads();
        if (threadIdx.x == 0) *xdt = (cnt > 128) ? 1 : 0;
    } else {
        int i = (blockIdx.x - 33) * 256 + threadIdx.x;   // 8192 words
        deg[i] = 0;
    }
}

// deg[d] = count of incoming edges (self loop added later as +1)
__global__ __launch_bounds__(256) void deg_kernel(const int* __restrict__ ei,
                                                  const int* __restrict__ eflagp,
                                                  int* __restrict__ deg) {
    int e = blockIdx.x * 256 + threadIdx.x;
    bool is64 = (*eflagp == 0);
    int d = is64 ? ei[2 * (N_EDGES + e)] : ei[N_EDGES + e];
    atomicAdd(&deg[d], 1);
}

// ---------------------------------------------------------------------------
// Exclusive prefix sum over deg[8192] -> offs[8193]; cursor = copy of offs.
// ---------------------------------------------------------------------------
__global__ __launch_bounds__(1024) void scan_kernel(const int* __restrict__ deg,
                                                    int* __restrict__ offs,
                                                    int* __restrict__ cursor) {
    __shared__ int part[1024];
    int t = threadIdx.x;
    int loc[8];
    int run = 0;
    #pragma unroll
    for (int j = 0; j < 8; ++j) { loc[j] = run; run += deg[t * 8 + j]; }
    part[t] = run;
    __syncthreads();
    for (int d = 1; d < 1024; d <<= 1) {
        int v = (t >= d) ? part[t - d] : 0;
        __syncthreads();
        part[t] += v;
        __syncthreads();
    }
    int pre = part[t] - run;                 // exclusive prefix of this chunk
    #pragma unroll
    for (int j = 0; j < 8; ++j) {
        int v = pre + loc[j];
        offs[t * 8 + j]   = v;
        cursor[t * 8 + j] = v;
    }
    if (t == 1023) offs[8192] = pre + run;   // == N_EDGES
}

// ---------------------------------------------------------------------------
// Merged: blocks 0..1023 bucket edges by dst (CSR fill); blocks 1024..1151
// compute h_scaled = dinv * (x^T W) and z = b + dinv * h_scaled.
// feat: 32768 threads, og = id>>13 (0..3, 16 outputs each), n = id & 8191.
// ---------------------------------------------------------------------------
__global__ __launch_bounds__(256) void fill_feat_kernel(
        const int* __restrict__ ei, const int* __restrict__ eflagp,
        int* __restrict__ cursor, int* __restrict__ esrc,
        const void* __restrict__ xv, const void* __restrict__ Wv,
        const void* __restrict__ bv, const int* __restrict__ xdtp,
        const int* __restrict__ deg,
        float* __restrict__ dinv,
        float* __restrict__ h,                  // [N][64], pre-scaled by dinv[n]
        float* __restrict__ z)                  // [N][64]
{
    __shared__ float Wl[F_IN * F_OUT];          // 32 KB
    int t = threadIdx.x;

    if (blockIdx.x < N_EDGES / 256) {
        // ---------------- CSR fill ----------------
        int e = blockIdx.x * 256 + t;
        bool is64 = (*eflagp == 0);
        int s = is64 ? ei[2 * e]             : ei[e];
        int d = is64 ? ei[2 * (N_EDGES + e)] : ei[N_EDGES + e];
        int pos = atomicAdd(&cursor[d], 1);
        esrc[pos] = s;
        return;
    }

    // ---------------- features ----------------
    const bool isbf = (*xdtp != 0);
    if (isbf) {
        const __hip_bfloat16* Wb = (const __hip_bfloat16*)Wv;
        for (int i = t; i < F_IN * F_OUT; i += 256) Wl[i] = (float)Wb[i];
    } else {
        const float* Wf = (const float*)Wv;
        for (int i = t; i < F_IN * F_OUT; i += 256) Wl[i] = Wf[i];
    }
    __syncthreads();

    int id = (blockIdx.x - N_EDGES / 256) * 256 + t;   // 0..32767
    int og = id >> 13;                          // 0..3, uniform within block
    int n  = id & (N_NODES - 1);

    float dv = rsqrtf((float)(deg[n] + 1));
    float acc[16];
    #pragma unroll
    for (int j = 0; j < 16; ++j) acc[j] = 0.f;

    if (isbf) {
        const __hip_bfloat16* xb = (const __hip_bfloat16*)xv;
        for (int f = 0; f < F_IN; ++f) {
            float xval = (float)xb[f * N_NODES + n];
            const float4* w4 = (const float4*)&Wl[f * F_OUT + og * 16];
            #pragma unroll
            for (int q = 0; q < 4; ++q) {
                float4 wv = w4[q];
                acc[q*4+0] += xval * wv.x; acc[q*4+1] += xval * wv.y;
                acc[q*4+2] += xval * wv.z; acc[q*4+3] += xval * wv.w;
            }
        }
    } else {
        const float* xf = (const float*)xv;
        for (int f = 0; f < F_IN; ++f) {
            float xval = xf[f * N_NODES + n];
            const float4* w4 = (const float4*)&Wl[f * F_OUT + og * 16];
            #pragma unroll
            for (int q = 0; q < 4; ++q) {
                float4 wv = w4[q];
                acc[q*4+0] += xval * wv.x; acc[q*4+1] += xval * wv.y;
                acc[q*4+2] += xval * wv.z; acc[q*4+3] += xval * wv.w;
            }
        }
    }

    if (og == 0) dinv[n] = dv;

    float bvals[16];
    if (isbf) {
        const __hip_bfloat16* bb = (const __hip_bfloat16*)bv;
        #pragma unroll
        for (int j = 0; j < 16; ++j) bvals[j] = (float)bb[og * 16 + j];
    } else {
        const float* bf = (const float*)bv;
        #pragma unroll
        for (int j = 0; j < 16; ++j) bvals[j] = bf[og * 16 + j];
    }
    float* hp = h + (size_t)n * 64 + og * 16;
    float* zp = z + (size_t)n * 64 + og * 16;
    #pragma unroll
    for (int q = 0; q < 4; ++q) {
        float hs[4], zb[4];
        #pragma unroll
        for (int j = 0; j < 4; ++j) {
            hs[j] = dv * acc[q*4+j];                 // pre-scaled message
            zb[j] = bvals[q*4+j] + dv * hs[j];       // self-loop term
        }
        ((float4*)hp)[q] = make_float4(hs[0], hs[1], hs[2], hs[3]);
        ((float4*)zp)[q] = make_float4(zb[0], zb[1], zb[2], zb[3]);
    }
}

// ---------------------------------------------------------------------------
// Gather aggregation: one wave per dst node, no atomics.
// Final z is packed IN PLACE as split-bf16: (hi<<16)|lo per element.
// ---------------------------------------------------------------------------
__global__ __launch_bounds__(256) void gather_kernel(
        const int* __restrict__ offs, const int* __restrict__ esrc,
        const float* __restrict__ h, const float* __restrict__ dinv,
        float* __restrict__ z)
{
    int t = blockIdx.x * 256 + threadIdx.x;
    int d = t >> 6;
    int o = t & 63;
    int beg = offs[d], end = offs[d + 1];
    float acc = 0.f;
    for (int i = beg; i < end; ++i) {
        int s = esrc[i];                         // wave-uniform
        acc += h[(size_t)s * 64 + o];            // coalesced 256B row
    }
    float fin = z[(size_t)d * 64 + o] + dinv[d] * acc;
    u16 hb = f2bf_rne(fin);
    u16 lb = f2bf_rne(fin - bf2f(hb));
    ((u32*)z)[(size_t)d * 64 + o] = ((u32)hb << 16) | (u32)lb;
}

// ---------------------------------------------------------------------------
// out = sigmoid(z @ z^T), split-bf16 MFMA (AhBh + AhBl + AlBh), symmetry:
// 2080 triangular blocks. Stage = 16x global_load_lds(16B) per thread of the
// PACKED zhl tiles (linear LDS dest + inverse-swizzled source, rule #21);
// hi/lo unpacked in-register via v_perm_b32. Mirrored tile via pad-129 LDS
// transpose. Output stores are nontemporal (out is never re-read; keep z
// resident in L2 instead).
// ---------------------------------------------------------------------------
__global__ __launch_bounds__(256) void gemm_sig_kernel(
        const u32* __restrict__ zhl, float* __restrict__ out)
{
    __shared__ __align__(16) u32 smem[128 * 129];   // 66048 B
    u32* Az = smem;                 // [128][16 chunks][4 u32], swizzled chunks
    u32* Bz = smem + 8192;
    float* Cs = (float*)smem;       // [128][129] alias for transpose phase

    int t    = threadIdx.x;
    int lane = t & 63;
    int w    = t >> 6;

    // triangular decode: blockIdx.x -> (bi, bj), bi >= bj
    int tgt = blockIdx.x;
    int bi = (int)((sqrtf(8.f * (float)tgt + 1.f) - 1.f) * 0.5f);
    while ((bi + 1) * (bi + 2) / 2 <= tgt) ++bi;
    while (bi * (bi + 1) / 2 > tgt) --bi;
    int bj = tgt - bi * (bi + 1) / 2;
    int i0 = bi * 128;
    int j0 = bj * 128;
    bool offdiag = (bi != bj);

    // ---- stage: async global->LDS, 32 wave-instrs per tile ---------------
    #pragma unroll
    for (int T = 0; T < 2; ++T) {
        int rbase = T ? j0 : i0;
        u32* dstT = T ? Bz : Az;
        #pragma unroll
        for (int jj = 0; jj < 8; ++jj) {
            int instr = w * 8 + jj;                // 0..31
            int q  = instr * 64 + lane;            // 16B-chunk id, 0..2047
            int r  = q >> 4;                       // row 0..127
            int ch = q & 15;                       // dest chunk
            int cs = ch ^ SWZ(r);                  // source chunk (involution)
            const u32* g = zhl + (size_t)(rbase + r) * 64 + cs * 4;
            __builtin_amdgcn_global_load_lds(g, dstT + instr * 256, 16, 0, 0);
        }
    }
    __syncthreads();

    // ---- frag reads + unpack ---------------------------------------------
    int lr = lane & 15;                       // row within 16x16 tile
    int lk = lane >> 4;                       // k sub-chunk 0..3

    short8 ah[2][2], al[2][2];                // [rt][kh]
    #pragma unroll
    for (int rt = 0; rt < 2; ++rt)
        #pragma unroll
        for (int kh = 0; kh < 2; ++kh) {
            int rl = w * 32 + rt * 16 + lr;
            int c0 = (kh * 4 + lk) * 2;
            u32x4 q0 = *(const u32x4*)&Az[rl * 64 + ((c0    ) ^ SWZ(rl)) * 4];
            u32x4 q1 = *(const u32x4*)&Az[rl * 64 + ((c0 + 1) ^ SWZ(rl)) * 4];
            u32 v[8] = {q0.x, q0.y, q0.z, q0.w, q1.x, q1.y, q1.z, q1.w};
            u32x4 hi, lo;
            #pragma unroll
            for (int j = 0; j < 4; ++j) {
                hi[j] = __builtin_amdgcn_perm(v[2*j+1], v[2*j], 0x07060302u);
                lo[j] = __builtin_amdgcn_perm(v[2*j+1], v[2*j], 0x05040100u);
            }
            ah[rt][kh] = __builtin_bit_cast(short8, hi);
            al[rt][kh] = __builtin_bit_cast(short8, lo);
        }

    f32x4 acc[2][8];
    #pragma unroll
    for (int rt = 0; rt < 2; ++rt)
        #pragma unroll
        for (int ct = 0; ct < 8; ++ct)
            acc[rt][ct] = (f32x4){0.f, 0.f, 0.f, 0.f};

    #pragma unroll
    for (int ct = 0; ct < 8; ++ct) {
        short8 bh[2], bl[2];
        #pragma unroll
        for (int kh = 0; kh < 2; ++kh) {
            int rl = ct * 16 + lr;
            int c0 = (kh * 4 + lk) * 2;
            u32x4 q0 = *(const u32x4*)&Bz[rl * 64 + ((c0    ) ^ SWZ(rl)) * 4];
            u32x4 q1 = *(const u32x4*)&Bz[rl * 64 + ((c0 + 1) ^ SWZ(rl)) * 4];
            u32 v[8] = {q0.x, q0.y, q0.z, q0.w, q1.x, q1.y, q1.z, q1.w};
            u32x4 hi, lo;
            #pragma unroll
            for (int j = 0; j < 4; ++j) {
                hi[j] = __builtin_amdgcn_perm(v[2*j+1], v[2*j], 0x07060302u);
                lo[j] = __builtin_amdgcn_perm(v[2*j+1], v[2*j], 0x05040100u);
            }
            bh[kh] = __builtin_bit_cast(short8, hi);
            bl[kh] = __builtin_bit_cast(short8, lo);
        }
        #pragma unroll
        for (int rt = 0; rt < 2; ++rt) {
            #pragma unroll
            for (int kh = 0; kh < 2; ++kh) {
                acc[rt][ct] = __builtin_amdgcn_mfma_f32_16x16x32_bf16(
                    ah[rt][kh], bh[kh], acc[rt][ct], 0, 0, 0);
                acc[rt][ct] = __builtin_amdgcn_mfma_f32_16x16x32_bf16(
                    ah[rt][kh], bl[kh], acc[rt][ct], 0, 0, 0);
                acc[rt][ct] = __builtin_amdgcn_mfma_f32_16x16x32_bf16(
                    al[rt][kh], bh[kh], acc[rt][ct], 0, 0, 0);
            }
        }
    }

    // ---- sigmoid in-register (exp + rcp, no div expansion) ----------------
    #pragma unroll
    for (int rt = 0; rt < 2; ++rt)
        #pragma unroll
        for (int ct = 0; ct < 8; ++ct)
            #pragma unroll
            for (int rg = 0; rg < 4; ++rg) {
                float v = acc[rt][ct][rg];
                acc[rt][ct][rg] = __builtin_amdgcn_rcpf(1.f + __expf(-v));
            }

    // ---- mirrored tile: stage sigmoid values into padded f32 LDS ----------
    if (offdiag) {
        __syncthreads();          // all frag reads done; safe to alias smem
        #pragma unroll
        for (int rt = 0; rt < 2; ++rt)
            #pragma unroll
            for (int ct = 0; ct < 8; ++ct) {
                int col = ct * 16 + lr;
                int row = w * 32 + rt * 16 + lk * 4;
                #pragma unroll
                for (int rg = 0; rg < 4; ++rg)
                    Cs[(row + rg) * 129 + col] = acc[rt][ct][rg];
            }
    }

    // ---- direct stores of the (i0,j0) tile: C/D layout, 64B segments ------
    #pragma unroll
    for (int rt = 0; rt < 2; ++rt)
        #pragma unroll
        for (int ct = 0; ct < 8; ++ct) {
            int gcol = j0 + ct * 16 + lr;
            #pragma unroll
            for (int rg = 0; rg < 4; ++rg) {
                int grow = i0 + w * 32 + rt * 16 + lk * 4 + rg;
                __builtin_nontemporal_store(acc[rt][ct][rg],
                    out + (size_t)grow * N_NODES + gcol);
            }
        }

    // ---- transposed float4 stores of the (j0,i0) tile ---------------------
    if (offdiag) {
        __syncthreads();
        #pragma unroll
        for (int u = 0; u < 16; ++u) {
            int q   = u * 256 + t;          // 0..4095
            int rr  = q >> 5;               // out^T row = LDS column, 0..127
            int cc4 = (q & 31) * 4;         // LDS row start, 0..124
            f32x4 v;
            v[0] = Cs[(cc4 + 0) * 129 + rr];
            v[1] = Cs[(cc4 + 1) * 129 + rr];
            v[2] = Cs[(cc4 + 2) * 129 + rr];
            v[3] = Cs[(cc4 + 3) * 129 + rr];
            __builtin_nontemporal_store(v,
                (f32x4*)(out + (size_t)(j0 + rr) * N_NODES + i0 + cc4));
        }
    }
}

// ---------------------------------------------------------------------------
extern "C" void kernel_launch(void* const* d_in, const int* in_sizes, int n_in,
                              void* d_out, int out_size, void* d_ws, size_t ws_size,
                              hipStream_t stream) {
    const void* x  = d_in[0];                 // fp32 [128][8192]
    const int*  ei = (const int*)d_in[1];     // int64 or int32 [2][262144]
    const void* W  = d_in[2];                 // fp32 [128][64]
    const void* b  = d_in[3];                 // fp32 [64]
    float* out = (float*)d_out;               // fp32 [8192][8192]

    char* ws = (char*)d_ws;
    int*   deg    = (int*)ws;                         // 32 KB
    int*   eflag  = (int*)(ws + 32768);               // 4 B
    int*   xdt    = (int*)(ws + 32784);               // 4 B
    int*   offs   = (int*)(ws + 36864);               // 8193*4 B
    int*   cursor = (int*)(ws + 73728);               // 32 KB
    float* dinv   = (float*)(ws + 110592);            // 32 KB
    int*   esrc   = (int*)(ws + 147456);              // 1 MB
    float* h      = (float*)(ws + 1196032);           // 2 MB
    float* z      = (float*)(ws + 3293184);           // 2 MB (ends ~5.14 MB)

    (void)hipMemsetAsync(ws + 32768, 0, 32, stream);  // eflag + xdt only
    init_kernel<<<65, 256, 0, stream>>>(ei, (const u32*)x, eflag, xdt, deg);
    deg_kernel<<<N_EDGES / 256, 256, 0, stream>>>(ei, eflag, deg);
    scan_kernel<<<1, 1024, 0, stream>>>(deg, offs, cursor);
    fill_feat_kernel<<<N_EDGES / 256 + 128, 256, 0, stream>>>(
        ei, eflag, cursor, esrc, x, W, b, xdt, deg, dinv, h, z);
    gather_kernel<<<N_NODES * 64 / 256, 256, 0, stream>>>(offs, esrc, h, dinv, z);
    gemm_sig_kernel<<<64 * 65 / 2, 256, 0, stream>>>((const u32*)z, out);
}

// Round 6
// 338.368 us; speedup vs baseline: 1.0715x; 1.0715x over previous
//
#include <hip/hip_runtime.h>
#include <hip/hip_bf16.h>

#define N_NODES 8192
#define F_IN    128
#define F_OUT   64
#define N_EDGES 262144

typedef unsigned int   u32;
typedef unsigned short u16;
typedef __attribute__((ext_vector_type(8))) short short8;
typedef __attribute__((ext_vector_type(4))) float f32x4;
typedef __attribute__((ext_vector_type(4))) u32 u32x4;

// chunk swizzle (16B chunks, 16 per row): XOR of a 3-bit mix of row bits.
// Involution in ch for fixed r; spreads 16-row frag reads across 8 bank-quads.
__device__ __forceinline__ int SWZ(int r) {
    return (((r) & 3) << 1) | (((r) >> 2) & 1);
}

__device__ __forceinline__ u16 f2bf_rne(float f) {
    u32 u = __float_as_uint(f);
    u32 r = (u + 0x7FFFu + ((u >> 16) & 1u)) >> 16;
    return (u16)r;
}
__device__ __forceinline__ float bf2f(u16 b) {
    return __uint_as_float(((u32)b) << 16);
}

// ---------------------------------------------------------------------------
// init: blocks 0..31 detect edge width; block 32 detects x dtype;
// blocks 33..64 zero deg[8192]. Flags pre-zeroed by a 32-B memset.
// ---------------------------------------------------------------------------
__global__ __launch_bounds__(256) void init_kernel(const int* __restrict__ ei,
                                                   const u32* __restrict__ xw,
                                                   int* __restrict__ eflag,
                                                   int* __restrict__ xdt,
                                                   int* __restrict__ deg) {
    if (blockIdx.x < 32) {
        int i = blockIdx.x * 256 + threadIdx.x;      // 8192 samples
        if (ei[2 * i + 1] != 0) atomicOr(eflag, 1);
    } else if (blockIdx.x == 32) {
        __shared__ int cnt;
        if (threadIdx.x == 0) cnt = 0;
        __syncthreads();
        u32 w = xw[threadIdx.x * 64 + 1];
        u32 e = (w >> 7) & 0xFFu;
        if (e >= 100u && e <= 134u) atomicAdd(&cnt, 1);
        __syncthreads();
        if (threadIdx.x == 0) *xdt = (cnt > 128) ? 1 : 0;
    } else {
        int i = (blockIdx.x - 33) * 256 + threadIdx.x;   // 8192 words
        deg[i] = 0;
    }
}

// deg[d] = count of incoming edges (self loop added later as +1)
__global__ __launch_bounds__(256) void deg_kernel(const int* __restrict__ ei,
                                                  const int* __restrict__ eflagp,
                                                  int* __restrict__ deg) {
    int e = blockIdx.x * 256 + threadIdx.x;
    bool is64 = (*eflagp == 0);
    int d = is64 ? ei[2 * (N_EDGES + e)] : ei[N_EDGES + e];
    atomicAdd(&deg[d], 1);
}

// ---------------------------------------------------------------------------
// Exclusive prefix sum over deg[8192] -> offs[8193]; cursor = copy of offs.
// ---------------------------------------------------------------------------
__global__ __launch_bounds__(1024) void scan_kernel(const int* __restrict__ deg,
                                                    int* __restrict__ offs,
                                                    int* __restrict__ cursor) {
    __shared__ int part[1024];
    int t = threadIdx.x;
    int loc[8];
    int run = 0;
    #pragma unroll
    for (int j = 0; j < 8; ++j) { loc[j] = run; run += deg[t * 8 + j]; }
    part[t] = run;
    __syncthreads();
    for (int d = 1; d < 1024; d <<= 1) {
        int v = (t >= d) ? part[t - d] : 0;
        __syncthreads();
        part[t] += v;
        __syncthreads();
    }
    int pre = part[t] - run;                 // exclusive prefix of this chunk
    #pragma unroll
    for (int j = 0; j < 8; ++j) {
        int v = pre + loc[j];
        offs[t * 8 + j]   = v;
        cursor[t * 8 + j] = v;
    }
    if (t == 1023) offs[8192] = pre + run;   // == N_EDGES
}

// ---------------------------------------------------------------------------
// Merged: blocks 0..1023 bucket edges by dst (CSR fill); blocks 1024..1151
// compute h_scaled = dinv * (x^T W) and z = b + dinv * h_scaled.
// feat: 32768 threads, og = id>>13 (0..3, 16 outputs each), n = id & 8191.
// ---------------------------------------------------------------------------
__global__ __launch_bounds__(256) void fill_feat_kernel(
        const int* __restrict__ ei, const int* __restrict__ eflagp,
        int* __restrict__ cursor, int* __restrict__ esrc,
        const void* __restrict__ xv, const void* __restrict__ Wv,
        const void* __restrict__ bv, const int* __restrict__ xdtp,
        const int* __restrict__ deg,
        float* __restrict__ dinv,
        float* __restrict__ h,                  // [N][64], pre-scaled by dinv[n]
        float* __restrict__ z)                  // [N][64]
{
    __shared__ float Wl[F_IN * F_OUT];          // 32 KB
    int t = threadIdx.x;

    if (blockIdx.x < N_EDGES / 256) {
        // ---------------- CSR fill ----------------
        int e = blockIdx.x * 256 + t;
        bool is64 = (*eflagp == 0);
        int s = is64 ? ei[2 * e]             : ei[e];
        int d = is64 ? ei[2 * (N_EDGES + e)] : ei[N_EDGES + e];
        int pos = atomicAdd(&cursor[d], 1);
        esrc[pos] = s;
        return;
    }

    // ---------------- features ----------------
    const bool isbf = (*xdtp != 0);
    if (isbf) {
        const __hip_bfloat16* Wb = (const __hip_bfloat16*)Wv;
        for (int i = t; i < F_IN * F_OUT; i += 256) Wl[i] = (float)Wb[i];
    } else {
        const float* Wf = (const float*)Wv;
        for (int i = t; i < F_IN * F_OUT; i += 256) Wl[i] = Wf[i];
    }
    __syncthreads();

    int id = (blockIdx.x - N_EDGES / 256) * 256 + t;   // 0..32767
    int og = id >> 13;                          // 0..3, uniform within block
    int n  = id & (N_NODES - 1);

    float dv = rsqrtf((float)(deg[n] + 1));
    float acc[16];
    #pragma unroll
    for (int j = 0; j < 16; ++j) acc[j] = 0.f;

    if (isbf) {
        const __hip_bfloat16* xb = (const __hip_bfloat16*)xv;
        for (int f = 0; f < F_IN; ++f) {
            float xval = (float)xb[f * N_NODES + n];
            const float4* w4 = (const float4*)&Wl[f * F_OUT + og * 16];
            #pragma unroll
            for (int q = 0; q < 4; ++q) {
                float4 wv = w4[q];
                acc[q*4+0] += xval * wv.x; acc[q*4+1] += xval * wv.y;
                acc[q*4+2] += xval * wv.z; acc[q*4+3] += xval * wv.w;
            }
        }
    } else {
        const float* xf = (const float*)xv;
        for (int f = 0; f < F_IN; ++f) {
            float xval = xf[f * N_NODES + n];
            const float4* w4 = (const float4*)&Wl[f * F_OUT + og * 16];
            #pragma unroll
            for (int q = 0; q < 4; ++q) {
                float4 wv = w4[q];
                acc[q*4+0] += xval * wv.x; acc[q*4+1] += xval * wv.y;
                acc[q*4+2] += xval * wv.z; acc[q*4+3] += xval * wv.w;
            }
        }
    }

    if (og == 0) dinv[n] = dv;

    float bvals[16];
    if (isbf) {
        const __hip_bfloat16* bb = (const __hip_bfloat16*)bv;
        #pragma unroll
        for (int j = 0; j < 16; ++j) bvals[j] = (float)bb[og * 16 + j];
    } else {
        const float* bf = (const float*)bv;
        #pragma unroll
        for (int j = 0; j < 16; ++j) bvals[j] = bf[og * 16 + j];
    }
    float* hp = h + (size_t)n * 64 + og * 16;
    float* zp = z + (size_t)n * 64 + og * 16;
    #pragma unroll
    for (int q = 0; q < 4; ++q) {
        float hs[4], zb[4];
        #pragma unroll
        for (int j = 0; j < 4; ++j) {
            hs[j] = dv * acc[q*4+j];                 // pre-scaled message
            zb[j] = bvals[q*4+j] + dv * hs[j];       // self-loop term
        }
        ((float4*)hp)[q] = make_float4(hs[0], hs[1], hs[2], hs[3]);
        ((float4*)zp)[q] = make_float4(zb[0], zb[1], zb[2], zb[3]);
    }
}

// ---------------------------------------------------------------------------
// Gather aggregation: one wave per dst node, no atomics. 4-way unrolled so
// 4 independent esrc + h-row loads are in flight (MLP) instead of a serial
// dependent chain. Final z packed IN PLACE as split-bf16: (hi<<16)|lo.
// ---------------------------------------------------------------------------
__global__ __launch_bounds__(256) void gather_kernel(
        const int* __restrict__ offs, const int* __restrict__ esrc,
        const float* __restrict__ h, const float* __restrict__ dinv,
        float* __restrict__ z)
{
    int t = blockIdx.x * 256 + threadIdx.x;
    int d = t >> 6;
    int o = t & 63;
    int beg = offs[d], end = offs[d + 1];
    float acc = 0.f;
    int i = beg;
    for (; i + 4 <= end; i += 4) {
        int s0 = esrc[i], s1 = esrc[i+1], s2 = esrc[i+2], s3 = esrc[i+3];
        float v0 = h[(size_t)s0 * 64 + o];
        float v1 = h[(size_t)s1 * 64 + o];
        float v2 = h[(size_t)s2 * 64 + o];
        float v3 = h[(size_t)s3 * 64 + o];
        acc += v0 + v1 + v2 + v3;
    }
    for (; i < end; ++i) {
        int s = esrc[i];
        acc += h[(size_t)s * 64 + o];
    }
    float fin = z[(size_t)d * 64 + o] + dinv[d] * acc;
    u16 hb = f2bf_rne(fin);
    u16 lb = f2bf_rne(fin - bf2f(hb));
    ((u32*)z)[(size_t)d * 64 + o] = ((u32)hb << 16) | (u32)lb;
}

// ---------------------------------------------------------------------------
// out = sigmoid(z @ z^T), split-bf16 MFMA (AhBh + AhBl + AlBh), symmetry:
// 2080 triangular blocks. Stage = 16x global_load_lds(16B) per thread of the
// PACKED zhl tiles (linear LDS dest + inverse-swizzled source, rule #21);
// hi/lo unpacked in-register via v_perm_b32. Mirrored tile via pad-129 LDS
// transpose. Direct-tile stores are PLAIN (L2 merges the 64B segments into
// full lines — nt here caused partial-line HBM writes, R4 regression);
// mirror float4 stores are nontemporal (full 1KB/wave-instr lines).
// ---------------------------------------------------------------------------
__global__ __launch_bounds__(256) void gemm_sig_kernel(
        const u32* __restrict__ zhl, float* __restrict__ out)
{
    __shared__ __align__(16) u32 smem[128 * 129];   // 66048 B
    u32* Az = smem;                 // [128][16 chunks][4 u32], swizzled chunks
    u32* Bz = smem + 8192;
    float* Cs = (float*)smem;       // [128][129] alias for transpose phase

    int t    = threadIdx.x;
    int lane = t & 63;
    int w    = t >> 6;

    // triangular decode: blockIdx.x -> (bi, bj), bi >= bj
    int tgt = blockIdx.x;
    int bi = (int)((sqrtf(8.f * (float)tgt + 1.f) - 1.f) * 0.5f);
    while ((bi + 1) * (bi + 2) / 2 <= tgt) ++bi;
    while (bi * (bi + 1) / 2 > tgt) --bi;
    int bj = tgt - bi * (bi + 1) / 2;
    int i0 = bi * 128;
    int j0 = bj * 128;
    bool offdiag = (bi != bj);

    // ---- stage: async global->LDS, 32 wave-instrs per tile ---------------
    #pragma unroll
    for (int T = 0; T < 2; ++T) {
        int rbase = T ? j0 : i0;
        u32* dstT = T ? Bz : Az;
        #pragma unroll
        for (int jj = 0; jj < 8; ++jj) {
            int instr = w * 8 + jj;                // 0..31
            int q  = instr * 64 + lane;            // 16B-chunk id, 0..2047
            int r  = q >> 4;                       // row 0..127
            int ch = q & 15;                       // dest chunk
            int cs = ch ^ SWZ(r);                  // source chunk (involution)
            const u32* g = zhl + (size_t)(rbase + r) * 64 + cs * 4;
            __builtin_amdgcn_global_load_lds(g, dstT + instr * 256, 16, 0, 0);
        }
    }
    __syncthreads();

    // ---- frag reads + unpack ---------------------------------------------
    int lr = lane & 15;                       // row within 16x16 tile
    int lk = lane >> 4;                       // k sub-chunk 0..3

    short8 ah[2][2], al[2][2];                // [rt][kh]
    #pragma unroll
    for (int rt = 0; rt < 2; ++rt)
        #pragma unroll
        for (int kh = 0; kh < 2; ++kh) {
            int rl = w * 32 + rt * 16 + lr;
            int c0 = (kh * 4 + lk) * 2;
            u32x4 q0 = *(const u32x4*)&Az[rl * 64 + ((c0    ) ^ SWZ(rl)) * 4];
            u32x4 q1 = *(const u32x4*)&Az[rl * 64 + ((c0 + 1) ^ SWZ(rl)) * 4];
            u32 v[8] = {q0.x, q0.y, q0.z, q0.w, q1.x, q1.y, q1.z, q1.w};
            u32x4 hi, lo;
            #pragma unroll
            for (int j = 0; j < 4; ++j) {
                hi[j] = __builtin_amdgcn_perm(v[2*j+1], v[2*j], 0x07060302u);
                lo[j] = __builtin_amdgcn_perm(v[2*j+1], v[2*j], 0x05040100u);
            }
            ah[rt][kh] = __builtin_bit_cast(short8, hi);
            al[rt][kh] = __builtin_bit_cast(short8, lo);
        }

    f32x4 acc[2][8];
    #pragma unroll
    for (int rt = 0; rt < 2; ++rt)
        #pragma unroll
        for (int ct = 0; ct < 8; ++ct)
            acc[rt][ct] = (f32x4){0.f, 0.f, 0.f, 0.f};

    #pragma unroll
    for (int ct = 0; ct < 8; ++ct) {
        short8 bh[2], bl[2];
        #pragma unroll
        for (int kh = 0; kh < 2; ++kh) {
            int rl = ct * 16 + lr;
            int c0 = (kh * 4 + lk) * 2;
            u32x4 q0 = *(const u32x4*)&Bz[rl * 64 + ((c0    ) ^ SWZ(rl)) * 4];
            u32x4 q1 = *(const u32x4*)&Bz[rl * 64 + ((c0 + 1) ^ SWZ(rl)) * 4];
            u32 v[8] = {q0.x, q0.y, q0.z, q0.w, q1.x, q1.y, q1.z, q1.w};
            u32x4 hi, lo;
            #pragma unroll
            for (int j = 0; j < 4; ++j) {
                hi[j] = __builtin_amdgcn_perm(v[2*j+1], v[2*j], 0x07060302u);
                lo[j] = __builtin_amdgcn_perm(v[2*j+1], v[2*j], 0x05040100u);
            }
            bh[kh] = __builtin_bit_cast(short8, hi);
            bl[kh] = __builtin_bit_cast(short8, lo);
        }
        #pragma unroll
        for (int rt = 0; rt < 2; ++rt) {
            #pragma unroll
            for (int kh = 0; kh < 2; ++kh) {
                acc[rt][ct] = __builtin_amdgcn_mfma_f32_16x16x32_bf16(
                    ah[rt][kh], bh[kh], acc[rt][ct], 0, 0, 0);
                acc[rt][ct] = __builtin_amdgcn_mfma_f32_16x16x32_bf16(
                    ah[rt][kh], bl[kh], acc[rt][ct], 0, 0, 0);
                acc[rt][ct] = __builtin_amdgcn_mfma_f32_16x16x32_bf16(
                    al[rt][kh], bh[kh], acc[rt][ct], 0, 0, 0);
            }
        }
    }

    // ---- sigmoid in-register (exp + rcp, no div expansion) ----------------
    #pragma unroll
    for (int rt = 0; rt < 2; ++rt)
        #pragma unroll
        for (int ct = 0; ct < 8; ++ct)
            #pragma unroll
            for (int rg = 0; rg < 4; ++rg) {
                float v = acc[rt][ct][rg];
                acc[rt][ct][rg] = __builtin_amdgcn_rcpf(1.f + __expf(-v));
            }

    // ---- mirrored tile: stage sigmoid values into padded f32 LDS ----------
    if (offdiag) {
        __syncthreads();          // all frag reads done; safe to alias smem
        #pragma unroll
        for (int rt = 0; rt < 2; ++rt)
            #pragma unroll
            for (int ct = 0; ct < 8; ++ct) {
                int col = ct * 16 + lr;
                int row = w * 32 + rt * 16 + lk * 4;
                #pragma unroll
                for (int rg = 0; rg < 4; ++rg)
                    Cs[(row + rg) * 129 + col] = acc[rt][ct][rg];
            }
    }

    // ---- direct stores of the (i0,j0) tile: C/D layout, 64B segments ------
    // PLAIN stores: L2 merges adjacent ct-chunks into full lines.
    #pragma unroll
    for (int rt = 0; rt < 2; ++rt)
        #pragma unroll
        for (int ct = 0; ct < 8; ++ct) {
            int gcol = j0 + ct * 16 + lr;
            #pragma unroll
            for (int rg = 0; rg < 4; ++rg) {
                int grow = i0 + w * 32 + rt * 16 + lk * 4 + rg;
                out[(size_t)grow * N_NODES + gcol] = acc[rt][ct][rg];
            }
        }

    // ---- transposed float4 stores of the (j0,i0) tile (full lines, nt) ----
    if (offdiag) {
        __syncthreads();
        #pragma unroll
        for (int u = 0; u < 16; ++u) {
            int q   = u * 256 + t;          // 0..4095
            int rr  = q >> 5;               // out^T row = LDS column, 0..127
            int cc4 = (q & 31) * 4;         // LDS row start, 0..124
            f32x4 v;
            v[0] = Cs[(cc4 + 0) * 129 + rr];
            v[1] = Cs[(cc4 + 1) * 129 + rr];
            v[2] = Cs[(cc4 + 2) * 129 + rr];
            v[3] = Cs[(cc4 + 3) * 129 + rr];
            __builtin_nontemporal_store(v,
                (f32x4*)(out + (size_t)(j0 + rr) * N_NODES + i0 + cc4));
        }
    }
}

// ---------------------------------------------------------------------------
extern "C" void kernel_launch(void* const* d_in, const int* in_sizes, int n_in,
                              void* d_out, int out_size, void* d_ws, size_t ws_size,
                              hipStream_t stream) {
    const void* x  = d_in[0];                 // fp32 [128][8192]
    const int*  ei = (const int*)d_in[1];     // int64 or int32 [2][262144]
    const void* W  = d_in[2];                 // fp32 [128][64]
    const void* b  = d_in[3];                 // fp32 [64]
    float* out = (float*)d_out;               // fp32 [8192][8192]

    char* ws = (char*)d_ws;
    int*   deg    = (int*)ws;                         // 32 KB
    int*   eflag  = (int*)(ws + 32768);               // 4 B
    int*   xdt    = (int*)(ws + 32784);               // 4 B
    int*   offs   = (int*)(ws + 36864);               // 8193*4 B
    int*   cursor = (int*)(ws + 73728);               // 32 KB
    float* dinv   = (float*)(ws + 110592);            // 32 KB
    int*   esrc   = (int*)(ws + 147456);              // 1 MB
    float* h      = (float*)(ws + 1196032);           // 2 MB
    float* z      = (float*)(ws + 3293184);           // 2 MB (ends ~5.14 MB)

    (void)hipMemsetAsync(ws + 32768, 0, 32, stream);  // eflag + xdt only
    init_kernel<<<65, 256, 0, stream>>>(ei, (const u32*)x, eflag, xdt, deg);
    deg_kernel<<<N_EDGES / 256, 256, 0, stream>>>(ei, eflag, deg);
    scan_kernel<<<1, 1024, 0, stream>>>(deg, offs, cursor);
    fill_feat_kernel<<<N_EDGES / 256 + 128, 256, 0, stream>>>(
        ei, eflag, cursor, esrc, x, W, b, xdt, deg, dinv, h, z);
    gather_kernel<<<N_NODES * 64 / 256, 256, 0, stream>>>(offs, esrc, h, dinv, z);
    gemm_sig_kernel<<<64 * 65 / 2, 256, 0, stream>>>((const u32*)z, out);
}